// Round 13
// baseline (308.952 us; speedup 1.0000x reference)
//
#include <hip/hip_runtime.h>

#define NEG_SLOPE 0.2f
#define BSHIFT 6            // bucket = dst >> 6 (64 nodes/bucket)
#define NBMAX 2048          // supports N <= 131072
#define BCAP 1408           // edges/bucket capacity (lambda=1024, +12 sigma)
#define ESTRIDE (BCAP + 64) // esrc slots per bucket (edges + self-loops)
#define CHUNK 4096          // edges per binning block

typedef __attribute__((ext_vector_type(8))) short short8;   // 8 bf16
typedef __attribute__((ext_vector_type(4))) float f32x4;

__device__ __forceinline__ unsigned short f2b(float x) {   // fp32 -> bf16 RNE
    unsigned u = __float_as_uint(x);
    u += 0x7fff + ((u >> 16) & 1);
    return (unsigned short)(u >> 16);
}
__device__ __forceinline__ float b2f(unsigned short u) {   // bf16 -> fp32
    return __uint_as_float((unsigned)u << 16);
}

// ===========================================================================
// One-shot weight conversion: W1 (64x128) and W2 (64x64) fp32 -> bf16.
// ===========================================================================
__global__ __launch_bounds__(256) void wconv_kernel(
    const float* __restrict__ W1, const float* __restrict__ W2,
    unsigned short* __restrict__ wb1, unsigned short* __restrict__ wb2)
{
    int i = blockIdx.x * 256 + threadIdx.x;
    if (i < 64 * 128) wb1[i] = f2b(W1[i]);
    else if (i < 64 * 128 + 64 * 64) wb2[i - 8192] = f2b(W2[i - 8192]);
}

// ===========================================================================
// Binning pass A: per-chunk LDS histogram -> hist[blk*NB + b].
// ===========================================================================
__global__ __launch_bounds__(256) void hist_kernel(
    const int* __restrict__ ei, int* __restrict__ hist, int E, int NB)
{
    __shared__ int cnt[NBMAX];
    const int tid = threadIdx.x;
    for (int i = tid; i < NB; i += 256) cnt[i] = 0;
    __syncthreads();
    const int start = blockIdx.x * CHUNK;
    const int end = min(start + CHUNK, E);
    for (int i = start + tid; i < end; i += 256)
        atomicAdd(&cnt[ei[E + i] >> BSHIFT], 1);
    __syncthreads();
    for (int i = tid; i < NB; i += 256)
        hist[(size_t)blockIdx.x * NB + i] = cnt[i];
}

// ===========================================================================
// Binning pass B: column exclusive-scan of hist (per bucket, over blocks).
// ===========================================================================
__global__ __launch_bounds__(256) void colscan_kernel(
    int* __restrict__ hist, int* __restrict__ btotal, int NB, int NBLK)
{
    const int b = blockIdx.x * 256 + threadIdx.x;
    if (b >= NB) return;
    int run = 0;
    int blk = 0;
    for (; blk + 8 <= NBLK; blk += 8) {
        int w[8];
        #pragma unroll
        for (int j = 0; j < 8; ++j) w[j] = hist[(size_t)(blk + j) * NB + b];
        #pragma unroll
        for (int j = 0; j < 8; ++j) {
            hist[(size_t)(blk + j) * NB + b] = run;
            run += w[j];
        }
    }
    for (; blk < NBLK; ++blk) {
        int w = hist[(size_t)blk * NB + b];
        hist[(size_t)blk * NB + b] = run;
        run += w;
    }
    btotal[b] = run;
}

// ===========================================================================
// Binning pass C: scatter edges into dense per-bucket segments.
// ===========================================================================
__global__ __launch_bounds__(256) void scatter_kernel(
    const int* __restrict__ ei, const int* __restrict__ hist,
    int* __restrict__ binned, int E, int NB)
{
    __shared__ int base[NBMAX], cnt2[NBMAX];
    const int tid = threadIdx.x;
    for (int i = tid; i < NB; i += 256) {
        base[i] = hist[(size_t)blockIdx.x * NB + i];
        cnt2[i] = 0;
    }
    __syncthreads();
    const int start = blockIdx.x * CHUNK;
    const int end = min(start + CHUNK, E);
    for (int i = start + tid; i < end; i += 256) {
        int s = ei[i], d = ei[E + i];
        int b = d >> BSHIFT;
        int r = base[b] + atomicAdd(&cnt2[b], 1);
        if (r < BCAP) binned[(size_t)b * BCAP + r] = (s << BSHIFT) | (d & 63);
    }
}

// ===========================================================================
// Per-bucket CSR finalize with FIXED-STRIDE esrc layout (no global scan):
// bucket b owns esrc[b*ESTRIDE ..]; row_beg/row_end per node. Self-loop first.
// ===========================================================================
__global__ __launch_bounds__(256) void bucket_csr_kernel(
    const int* __restrict__ binned, const int* __restrict__ btotal,
    int* __restrict__ row_beg, int* __restrict__ row_end,
    int* __restrict__ esrc, int N)
{
    __shared__ int ldeg[64];
    __shared__ int lcur[64];
    const int b = blockIdx.x;
    const int tid = threadIdx.x;
    const int node0 = b << BSHIFT;
    const int cnt = min(btotal[b], BCAP);
    const int base_e = b * ESTRIDE;
    const int* bp = binned + (size_t)b * BCAP;

    if (tid < 64) ldeg[tid] = (node0 + tid < N) ? 1 : 0;   // self-loop
    __syncthreads();
    for (int i = tid; i < cnt; i += 256)
        atomicAdd(&ldeg[bp[i] & 63], 1);
    __syncthreads();
    if (tid < 64) {                                        // wave 0: scan 64
        int v = ldeg[tid];
        int inc = v;
        #pragma unroll
        for (int off = 1; off < 64; off <<= 1) {
            int t2 = __shfl_up(inc, off, 64);
            if (tid >= off) inc += t2;
        }
        int excl = inc - v;
        int node = node0 + tid;
        if (node < N) {
            row_beg[node] = base_e + excl;
            row_end[node] = base_e + inc;
            esrc[base_e + excl] = node;                    // self-loop first
            lcur[tid] = base_e + excl + 1;
        }
    }
    __syncthreads();
    for (int i = tid; i < cnt; i += 256) {
        int v = bp[i];
        int pos = atomicAdd(&lcur[v & 63], 1);
        esrc[pos] = v >> BSHIFT;
    }
}

// ===========================================================================
// MFMA GEMM: h = in @ W.T (W pre-converted bf16, row-major [64][K]).
// Block = 64 nodes x 64 feats, wave = 16 nodes x 64 feats.
// v_mfma_f32_16x16x32_bf16; C/D: col=lane&15, row=quad*4+reg [m89].
// ===========================================================================
template<int K, bool BF16IN>
__global__ __launch_bounds__(256) void gemm_attn_kernel(
    const void* __restrict__ in_v, const unsigned short* __restrict__ Wb,
    const float* __restrict__ a_src, const float* __restrict__ a_dst,
    unsigned short* __restrict__ hb, float* __restrict__ asrc,
    float* __restrict__ adst, int N)
{
    constexpr int LDK = K + 8;               // shorts; rows stay 16B-aligned
    __shared__ unsigned short xb[64 * LDK];
    __shared__ unsigned short wb[64 * LDK];
    __shared__ float avs[64], avd[64];

    const int tid = threadIdx.x;
    const int node0 = blockIdx.x * 64;
    const int w = tid >> 6;
    const int lane = tid & 63;
    const int col = lane & 15;
    const int quad = lane >> 4;

    if (tid < 64) { avs[tid] = a_src[tid]; avd[tid] = a_dst[tid]; }

    // ---- stage W: plain 16B copies (pre-converted bf16) ----
    for (int i = tid; i < 64 * (K / 8); i += 256) {
        int r = i / (K / 8), c = i % (K / 8);
        *(ulonglong2*)&wb[r * LDK + 8 * c] = *(const ulonglong2*)&Wb[(size_t)r * K + 8 * c];
    }
    // ---- stage x ----
    if (BF16IN) {
        const unsigned short* in = (const unsigned short*)in_v;
        for (int i = tid; i < 64 * (K / 8); i += 256) {
            int r = i / (K / 8), c = i % (K / 8);
            int node = node0 + r;
            ulonglong2 v = (node < N)
                ? *(const ulonglong2*)&in[(size_t)node * K + 8 * c]
                : make_ulonglong2(0ull, 0ull);
            *(ulonglong2*)&xb[r * LDK + 8 * c] = v;
        }
    } else {
        const float* in = (const float*)in_v;
        for (int i = tid; i < 64 * (K / 4); i += 256) {
            int r = i / (K / 4), c = i % (K / 4);
            int node = node0 + r;
            float4 v = (node < N) ? *(const float4*)&in[(size_t)node * K + 4 * c]
                                  : make_float4(0.f, 0.f, 0.f, 0.f);
            *(ushort4*)&xb[r * LDK + 4 * c] =
                make_ushort4(f2b(v.x), f2b(v.y), f2b(v.z), f2b(v.w));
        }
    }
    __syncthreads();

    f32x4 acc[4] = {f32x4{0,0,0,0}, f32x4{0,0,0,0}, f32x4{0,0,0,0}, f32x4{0,0,0,0}};
    #pragma unroll
    for (int kc = 0; kc < K / 32; ++kc) {
        short8 a = *(const short8*)&xb[(16 * w + col) * LDK + kc * 32 + quad * 8];
        #pragma unroll
        for (int j = 0; j < 4; ++j) {
            short8 b = *(const short8*)&wb[(16 * j + col) * LDK + kc * 32 + quad * 8];
            acc[j] = __builtin_amdgcn_mfma_f32_16x16x32_bf16(a, b, acc[j], 0, 0, 0);
        }
    }

    #pragma unroll
    for (int r = 0; r < 4; ++r) {
        const int node = node0 + 16 * w + quad * 4 + r;
        const bool valid = node < N;
        float vs = 0.f, vd = 0.f;
        #pragma unroll
        for (int j = 0; j < 4; ++j) {
            float hv = acc[j][r];
            int f = 16 * j + col;
            if (valid) hb[(size_t)node * 64 + f] = f2b(hv);
            vs = fmaf(hv, avs[f], vs);
            vd = fmaf(hv, avd[f], vd);
        }
        #pragma unroll
        for (int off = 8; off >= 1; off >>= 1) {
            vs += __shfl_down(vs, off, 16);
            vd += __shfl_down(vd, off, 16);
        }
        if (col == 0 && valid) { asrc[node] = vs; adst[node] = vd; }
    }
}

// ===========================================================================
// CSR aggregation: 16 lanes per dst node, 4 feats/lane, register acc,
// 8 edge chains in flight, bf16 h gathers.
// POOL=false: write bf16 g rows (+bias+relu). POOL=true: skip g entirely,
// block-reduce into partials[block][64] for the final mean-pool.
// ===========================================================================
template<bool POOL>
__global__ __launch_bounds__(256) void aggregate_csr_kernel(
    const int* __restrict__ row_beg, const int* __restrict__ row_end,
    const int* __restrict__ esrc,
    const float* __restrict__ asrc, const float* __restrict__ adst,
    const unsigned short* __restrict__ hb, const float* __restrict__ bias,
    unsigned short* __restrict__ gb, float* __restrict__ partials, int N)
{
    __shared__ float psum[64];
    if (POOL) {
        if (threadIdx.x < 64) psum[threadIdx.x] = 0.f;
        __syncthreads();
    }
    const int node = (int)((blockIdx.x * 256 + threadIdx.x) >> 4);
    const int lane = threadIdx.x & 15;
    if (node < N) {
        const int beg = row_beg[node];
        const int end = row_end[node];
        const float ad = adst[node];
        float a0 = 0.f, a1 = 0.f, a2 = 0.f, a3 = 0.f, wsum = 0.f;
        int p = beg;
        for (; p + 8 <= end; p += 8) {
            int s[8]; ushort4 r[8]; float l[8];
            #pragma unroll
            for (int j = 0; j < 8; ++j) s[j] = esrc[p + j];
            #pragma unroll
            for (int j = 0; j < 8; ++j)
                r[j] = *(const ushort4*)(hb + (size_t)s[j] * 64 + lane * 4);
            #pragma unroll
            for (int j = 0; j < 8; ++j) l[j] = asrc[s[j]] + ad;
            #pragma unroll
            for (int j = 0; j < 8; ++j) {
                float ll = (l[j] > 0.f) ? l[j] : NEG_SLOPE * l[j];
                float w = __expf(ll);
                wsum += w;
                a0 = fmaf(w, b2f(r[j].x), a0);
                a1 = fmaf(w, b2f(r[j].y), a1);
                a2 = fmaf(w, b2f(r[j].z), a2);
                a3 = fmaf(w, b2f(r[j].w), a3);
            }
        }
        for (; p < end; ++p) {
            int s = esrc[p];
            ushort4 r = *(const ushort4*)(hb + (size_t)s * 64 + lane * 4);
            float l = asrc[s] + ad;
            l = (l > 0.f) ? l : NEG_SLOPE * l;
            float w = __expf(l);
            wsum += w;
            a0 = fmaf(w, b2f(r.x), a0);
            a1 = fmaf(w, b2f(r.y), a1);
            a2 = fmaf(w, b2f(r.z), a2);
            a3 = fmaf(w, b2f(r.w), a3);
        }
        const float inv = 1.0f / wsum;
        float4 v = make_float4(a0 * inv, a1 * inv, a2 * inv, a3 * inv);
        if (!POOL) {
            if (bias) {
                v.x += bias[lane * 4 + 0]; v.y += bias[lane * 4 + 1];
                v.z += bias[lane * 4 + 2]; v.w += bias[lane * 4 + 3];
            }
            v.x = fmaxf(v.x, 0.f); v.y = fmaxf(v.y, 0.f);
            v.z = fmaxf(v.z, 0.f); v.w = fmaxf(v.w, 0.f);
            *(ushort4*)&gb[(size_t)node * 64 + lane * 4] =
                make_ushort4(f2b(v.x), f2b(v.y), f2b(v.z), f2b(v.w));
        } else {
            atomicAdd(&psum[lane * 4 + 0], v.x);
            atomicAdd(&psum[lane * 4 + 1], v.y);
            atomicAdd(&psum[lane * 4 + 2], v.z);
            atomicAdd(&psum[lane * 4 + 3], v.w);
        }
    }
    if (POOL) {
        __syncthreads();
        if (threadIdx.x < 64)
            partials[(size_t)blockIdx.x * 64 + threadIdx.x] = psum[threadIdx.x];
    }
}

// ===========================================================================
// Final mean-pool: out[f] = sum_blocks(partials)/N + b2[f]
// ===========================================================================
__global__ __launch_bounds__(256) void pool_final_kernel(
    const float* __restrict__ partials, const float* __restrict__ b2,
    float* __restrict__ out, int nblk, int N)
{
    __shared__ float red[256];
    const int f = threadIdx.x & 63;
    const int sub = threadIdx.x >> 6;
    float acc = 0.f;
    for (int r = blockIdx.x * 4 + sub; r < nblk; r += gridDim.x * 4)
        acc += partials[(size_t)r * 64 + f];
    red[threadIdx.x] = acc;
    __syncthreads();
    if (threadIdx.x < 64) {
        float s = red[f] + red[64 + f] + red[128 + f] + red[192 + f];
        atomicAdd(out + f, s * (1.0f / (float)N));
        if (blockIdx.x == 0) atomicAdd(out + f, b2[f]);
    }
}

extern "C" void kernel_launch(void* const* d_in, const int* in_sizes, int n_in,
                              void* d_out, int out_size, void* d_ws, size_t ws_size,
                              hipStream_t stream) {
    const float* x   = (const float*)d_in[0];
    const int*   ei  = (const int*)d_in[1];
    const float* W1  = (const float*)d_in[3];
    const float* as1 = (const float*)d_in[4];
    const float* ad1 = (const float*)d_in[5];
    const float* b1  = (const float*)d_in[6];
    const float* W2  = (const float*)d_in[7];
    const float* as2 = (const float*)d_in[8];
    const float* ad2 = (const float*)d_in[9];
    const float* b2  = (const float*)d_in[10];
    float* out = (float*)d_out;

    const int N = in_sizes[0] / 128;     // 100000
    const int E = in_sizes[1] / 2;       // 1600000
    const int NB = (N + 63) >> BSHIFT;   // 1563 buckets
    const int NBLK = (E + CHUNK - 1) / CHUNK;  // 391 binning blocks
    const int agg_blocks = (int)(((size_t)N * 16 + 255) / 256);   // 6250

    auto align4 = [](size_t v) { return (v + 3) & ~(size_t)3; };
    float* ws    = (float*)d_ws;
    size_t off = 0;
    unsigned short* hb = (unsigned short*)(ws + off); off += align4((size_t)N * 32);
    unsigned short* gb = (unsigned short*)(ws + off); off += align4((size_t)N * 32);
    float* asrc  = ws + off; off += align4(N);
    float* adst  = ws + off; off += align4(N);
    int* row_beg = (int*)(ws + off); off += align4(N);
    int* row_end = (int*)(ws + off); off += align4(N);
    int* btotal  = (int*)(ws + off); off += NBMAX;
    unsigned short* wb1 = (unsigned short*)(ws + off); off += align4(64 * 128 / 2);
    unsigned short* wb2 = (unsigned short*)(ws + off); off += align4(64 * 64 / 2);
    float* partials = ws + off; off += align4((size_t)agg_blocks * 64);
    int* hist    = (int*)(ws + off); off += align4((size_t)NBLK * NB);
    int* esrc    = (int*)(ws + off); off += align4((size_t)NB * ESTRIDE);
    int* binned  = (int*)gb;  // alias: gb dead until aggregate-1 writes it

    const int gemm_blocks = (N + 63) / 64;

    hipMemsetAsync(out, 0, 64 * sizeof(float), stream);
    wconv_kernel<<<48, 256, 0, stream>>>(W1, W2, wb1, wb2);

    // ---- CSR build: 4 kernels, zero contended global atomics ----
    hist_kernel<<<NBLK, 256, 0, stream>>>(ei, hist, E, NB);
    colscan_kernel<<<(NB + 255) / 256, 256, 0, stream>>>(hist, btotal, NB, NBLK);
    scatter_kernel<<<NBLK, 256, 0, stream>>>(ei, hist, binned, E, NB);
    bucket_csr_kernel<<<NB, 256, 0, stream>>>(binned, btotal, row_beg, row_end, esrc, N);

    // ---- layer 1 ----
    gemm_attn_kernel<128, false><<<gemm_blocks, 256, 0, stream>>>(
        x, wb1, as1, ad1, hb, asrc, adst, N);
    aggregate_csr_kernel<false><<<agg_blocks, 256, 0, stream>>>(
        row_beg, row_end, esrc, asrc, adst, hb, b1, gb, nullptr, N);

    // ---- layer 2 (aggregation fused with pooling partials) ----
    gemm_attn_kernel<64, true><<<gemm_blocks, 256, 0, stream>>>(
        gb, wb2, as2, ad2, hb, asrc, adst, N);
    aggregate_csr_kernel<true><<<agg_blocks, 256, 0, stream>>>(
        row_beg, row_end, esrc, asrc, adst, hb, nullptr, nullptr, partials, N);

    // ---- final mean pool + bias ----
    pool_final_kernel<<<64, 256, 0, stream>>>(partials, b2, out, agg_blocks, N);
}

// Round 14
// 306.923 us; speedup vs baseline: 1.0066x; 1.0066x over previous
//
#include <hip/hip_runtime.h>

#define NEG_SLOPE 0.2f
#define BSHIFT 6            // bucket = dst >> 6 (64 nodes/bucket)
#define NBMAX 2048          // supports N <= 131072
#define BCAP 1408           // edges/bucket capacity (lambda=1024, +12 sigma)
#define ESTRIDE (BCAP + 64) // esrc slots per bucket (edges + self-loops)
#define CHUNK 4096          // edges per binning block

typedef __attribute__((ext_vector_type(8))) short short8;   // 8 bf16
typedef __attribute__((ext_vector_type(4))) float f32x4;

__device__ __forceinline__ unsigned short f2b(float x) {   // fp32 -> bf16 RNE
    unsigned u = __float_as_uint(x);
    u += 0x7fff + ((u >> 16) & 1);
    return (unsigned short)(u >> 16);
}
__device__ __forceinline__ float b2f(unsigned short u) {   // bf16 -> fp32
    return __uint_as_float((unsigned)u << 16);
}

// ===========================================================================
// One-shot weight conversion: W1 (64x128) and W2 (64x64) fp32 -> bf16.
// ===========================================================================
__global__ __launch_bounds__(256) void wconv_kernel(
    const float* __restrict__ W1, const float* __restrict__ W2,
    unsigned short* __restrict__ wb1, unsigned short* __restrict__ wb2)
{
    int i = blockIdx.x * 256 + threadIdx.x;
    if (i < 64 * 128) wb1[i] = f2b(W1[i]);
    else if (i < 64 * 128 + 64 * 64) wb2[i - 8192] = f2b(W2[i - 8192]);
}

// ===========================================================================
// Binning pass A: per-chunk LDS histogram -> hist[blk*NB + b].
// ===========================================================================
__global__ __launch_bounds__(256) void hist_kernel(
    const int* __restrict__ ei, int* __restrict__ hist, int E, int NB)
{
    __shared__ int cnt[NBMAX];
    const int tid = threadIdx.x;
    for (int i = tid; i < NB; i += 256) cnt[i] = 0;
    __syncthreads();
    const int start = blockIdx.x * CHUNK;
    const int end = min(start + CHUNK, E);
    for (int i = start + tid; i < end; i += 256)
        atomicAdd(&cnt[ei[E + i] >> BSHIFT], 1);
    __syncthreads();
    for (int i = tid; i < NB; i += 256)
        hist[(size_t)blockIdx.x * NB + i] = cnt[i];
}

// ===========================================================================
// Binning pass B: column exclusive-scan of hist (per bucket, over blocks).
// ===========================================================================
__global__ __launch_bounds__(256) void colscan_kernel(
    int* __restrict__ hist, int* __restrict__ btotal, int NB, int NBLK)
{
    const int b = blockIdx.x * 256 + threadIdx.x;
    if (b >= NB) return;
    int run = 0;
    int blk = 0;
    for (; blk + 8 <= NBLK; blk += 8) {
        int w[8];
        #pragma unroll
        for (int j = 0; j < 8; ++j) w[j] = hist[(size_t)(blk + j) * NB + b];
        #pragma unroll
        for (int j = 0; j < 8; ++j) {
            hist[(size_t)(blk + j) * NB + b] = run;
            run += w[j];
        }
    }
    for (; blk < NBLK; ++blk) {
        int w = hist[(size_t)blk * NB + b];
        hist[(size_t)blk * NB + b] = run;
        run += w;
    }
    btotal[b] = run;
}

// ===========================================================================
// Binning pass C: scatter edges into dense per-bucket segments.
// ===========================================================================
__global__ __launch_bounds__(256) void scatter_kernel(
    const int* __restrict__ ei, const int* __restrict__ hist,
    int* __restrict__ binned, int E, int NB)
{
    __shared__ int base[NBMAX], cnt2[NBMAX];
    const int tid = threadIdx.x;
    for (int i = tid; i < NB; i += 256) {
        base[i] = hist[(size_t)blockIdx.x * NB + i];
        cnt2[i] = 0;
    }
    __syncthreads();
    const int start = blockIdx.x * CHUNK;
    const int end = min(start + CHUNK, E);
    for (int i = start + tid; i < end; i += 256) {
        int s = ei[i], d = ei[E + i];
        int b = d >> BSHIFT;
        int r = base[b] + atomicAdd(&cnt2[b], 1);
        if (r < BCAP) binned[(size_t)b * BCAP + r] = (s << BSHIFT) | (d & 63);
    }
}

// ===========================================================================
// Per-bucket CSR finalize with FIXED-STRIDE esrc layout (no global scan):
// bucket b owns esrc[b*ESTRIDE ..]; row_beg/row_end per node. Self-loop first.
// ===========================================================================
__global__ __launch_bounds__(256) void bucket_csr_kernel(
    const int* __restrict__ binned, const int* __restrict__ btotal,
    int* __restrict__ row_beg, int* __restrict__ row_end,
    int* __restrict__ esrc, int N)
{
    __shared__ int ldeg[64];
    __shared__ int lcur[64];
    const int b = blockIdx.x;
    const int tid = threadIdx.x;
    const int node0 = b << BSHIFT;
    const int cnt = min(btotal[b], BCAP);
    const int base_e = b * ESTRIDE;
    const int* bp = binned + (size_t)b * BCAP;

    if (tid < 64) ldeg[tid] = (node0 + tid < N) ? 1 : 0;   // self-loop
    __syncthreads();
    for (int i = tid; i < cnt; i += 256)
        atomicAdd(&ldeg[bp[i] & 63], 1);
    __syncthreads();
    if (tid < 64) {                                        // wave 0: scan 64
        int v = ldeg[tid];
        int inc = v;
        #pragma unroll
        for (int off = 1; off < 64; off <<= 1) {
            int t2 = __shfl_up(inc, off, 64);
            if (tid >= off) inc += t2;
        }
        int excl = inc - v;
        int node = node0 + tid;
        if (node < N) {
            row_beg[node] = base_e + excl;
            row_end[node] = base_e + inc;
            esrc[base_e + excl] = node;                    // self-loop first
            lcur[tid] = base_e + excl + 1;
        }
    }
    __syncthreads();
    for (int i = tid; i < cnt; i += 256) {
        int v = bp[i];
        int pos = atomicAdd(&lcur[v & 63], 1);
        esrc[pos] = v >> BSHIFT;
    }
}

// ===========================================================================
// MFMA GEMM: h = in @ W.T (W pre-converted bf16, row-major [64][K]).
// Block = 64 nodes x 64 feats, wave = 16 nodes x 64 feats.
// v_mfma_f32_16x16x32_bf16; C/D: col=lane&15, row=quad*4+reg [m89].
// ===========================================================================
template<int K, bool BF16IN>
__global__ __launch_bounds__(256) void gemm_attn_kernel(
    const void* __restrict__ in_v, const unsigned short* __restrict__ Wb,
    const float* __restrict__ a_src, const float* __restrict__ a_dst,
    unsigned short* __restrict__ hb, float* __restrict__ asrc,
    float* __restrict__ adst, int N)
{
    constexpr int LDK = K + 8;               // shorts; rows stay 16B-aligned
    __shared__ unsigned short xb[64 * LDK];
    __shared__ unsigned short wb[64 * LDK];
    __shared__ float avs[64], avd[64];

    const int tid = threadIdx.x;
    const int node0 = blockIdx.x * 64;
    const int w = tid >> 6;
    const int lane = tid & 63;
    const int col = lane & 15;
    const int quad = lane >> 4;

    if (tid < 64) { avs[tid] = a_src[tid]; avd[tid] = a_dst[tid]; }

    // ---- stage W: plain 16B copies (pre-converted bf16) ----
    for (int i = tid; i < 64 * (K / 8); i += 256) {
        int r = i / (K / 8), c = i % (K / 8);
        *(ulonglong2*)&wb[r * LDK + 8 * c] = *(const ulonglong2*)&Wb[(size_t)r * K + 8 * c];
    }
    // ---- stage x ----
    if (BF16IN) {
        const unsigned short* in = (const unsigned short*)in_v;
        for (int i = tid; i < 64 * (K / 8); i += 256) {
            int r = i / (K / 8), c = i % (K / 8);
            int node = node0 + r;
            ulonglong2 v = (node < N)
                ? *(const ulonglong2*)&in[(size_t)node * K + 8 * c]
                : make_ulonglong2(0ull, 0ull);
            *(ulonglong2*)&xb[r * LDK + 8 * c] = v;
        }
    } else {
        const float* in = (const float*)in_v;
        for (int i = tid; i < 64 * (K / 4); i += 256) {
            int r = i / (K / 4), c = i % (K / 4);
            int node = node0 + r;
            float4 v = (node < N) ? *(const float4*)&in[(size_t)node * K + 4 * c]
                                  : make_float4(0.f, 0.f, 0.f, 0.f);
            *(ushort4*)&xb[r * LDK + 4 * c] =
                make_ushort4(f2b(v.x), f2b(v.y), f2b(v.z), f2b(v.w));
        }
    }
    __syncthreads();

    f32x4 acc[4] = {f32x4{0,0,0,0}, f32x4{0,0,0,0}, f32x4{0,0,0,0}, f32x4{0,0,0,0}};
    #pragma unroll
    for (int kc = 0; kc < K / 32; ++kc) {
        short8 a = *(const short8*)&xb[(16 * w + col) * LDK + kc * 32 + quad * 8];
        #pragma unroll
        for (int j = 0; j < 4; ++j) {
            short8 b = *(const short8*)&wb[(16 * j + col) * LDK + kc * 32 + quad * 8];
            acc[j] = __builtin_amdgcn_mfma_f32_16x16x32_bf16(a, b, acc[j], 0, 0, 0);
        }
    }

    #pragma unroll
    for (int r = 0; r < 4; ++r) {
        const int node = node0 + 16 * w + quad * 4 + r;
        const bool valid = node < N;
        float vs = 0.f, vd = 0.f;
        #pragma unroll
        for (int j = 0; j < 4; ++j) {
            float hv = acc[j][r];
            int f = 16 * j + col;
            if (valid) hb[(size_t)node * 64 + f] = f2b(hv);
            vs = fmaf(hv, avs[f], vs);
            vd = fmaf(hv, avd[f], vd);
        }
        #pragma unroll
        for (int off = 8; off >= 1; off >>= 1) {
            vs += __shfl_down(vs, off, 16);
            vd += __shfl_down(vd, off, 16);
        }
        if (col == 0 && valid) { asrc[node] = vs; adst[node] = vd; }
    }
}

// ===========================================================================
// CSR aggregation: 16 lanes per dst node, 4 feats/lane, register acc,
// 4 edge chains in flight (8 regressed: VGPR cap serialized the batches —
// r13 post-mortem), bf16 h gathers.
// POOL=false: write bf16 g rows (+bias+relu). POOL=true: skip g entirely,
// block-reduce into partials[block][64] for the final mean-pool.
// ===========================================================================
template<bool POOL>
__global__ __launch_bounds__(256) void aggregate_csr_kernel(
    const int* __restrict__ row_beg, const int* __restrict__ row_end,
    const int* __restrict__ esrc,
    const float* __restrict__ asrc, const float* __restrict__ adst,
    const unsigned short* __restrict__ hb, const float* __restrict__ bias,
    unsigned short* __restrict__ gb, float* __restrict__ partials, int N)
{
    __shared__ float psum[64];
    if (POOL) {
        if (threadIdx.x < 64) psum[threadIdx.x] = 0.f;
        __syncthreads();
    }
    const int node = (int)((blockIdx.x * 256 + threadIdx.x) >> 4);
    const int lane = threadIdx.x & 15;
    if (node < N) {
        const int beg = row_beg[node];
        const int end = row_end[node];
        const float ad = adst[node];
        float a0 = 0.f, a1 = 0.f, a2 = 0.f, a3 = 0.f, wsum = 0.f;
        int p = beg;
        for (; p + 4 <= end; p += 4) {
            int s[4]; ushort4 r[4]; float l[4];
            #pragma unroll
            for (int j = 0; j < 4; ++j) s[j] = esrc[p + j];
            #pragma unroll
            for (int j = 0; j < 4; ++j)
                r[j] = *(const ushort4*)(hb + (size_t)s[j] * 64 + lane * 4);
            #pragma unroll
            for (int j = 0; j < 4; ++j) l[j] = asrc[s[j]] + ad;
            #pragma unroll
            for (int j = 0; j < 4; ++j) {
                float ll = (l[j] > 0.f) ? l[j] : NEG_SLOPE * l[j];
                float w = __expf(ll);
                wsum += w;
                a0 = fmaf(w, b2f(r[j].x), a0);
                a1 = fmaf(w, b2f(r[j].y), a1);
                a2 = fmaf(w, b2f(r[j].z), a2);
                a3 = fmaf(w, b2f(r[j].w), a3);
            }
        }
        for (; p < end; ++p) {
            int s = esrc[p];
            ushort4 r = *(const ushort4*)(hb + (size_t)s * 64 + lane * 4);
            float l = asrc[s] + ad;
            l = (l > 0.f) ? l : NEG_SLOPE * l;
            float w = __expf(l);
            wsum += w;
            a0 = fmaf(w, b2f(r.x), a0);
            a1 = fmaf(w, b2f(r.y), a1);
            a2 = fmaf(w, b2f(r.z), a2);
            a3 = fmaf(w, b2f(r.w), a3);
        }
        const float inv = 1.0f / wsum;
        float4 v = make_float4(a0 * inv, a1 * inv, a2 * inv, a3 * inv);
        if (!POOL) {
            if (bias) {
                v.x += bias[lane * 4 + 0]; v.y += bias[lane * 4 + 1];
                v.z += bias[lane * 4 + 2]; v.w += bias[lane * 4 + 3];
            }
            v.x = fmaxf(v.x, 0.f); v.y = fmaxf(v.y, 0.f);
            v.z = fmaxf(v.z, 0.f); v.w = fmaxf(v.w, 0.f);
            *(ushort4*)&gb[(size_t)node * 64 + lane * 4] =
                make_ushort4(f2b(v.x), f2b(v.y), f2b(v.z), f2b(v.w));
        } else {
            atomicAdd(&psum[lane * 4 + 0], v.x);
            atomicAdd(&psum[lane * 4 + 1], v.y);
            atomicAdd(&psum[lane * 4 + 2], v.z);
            atomicAdd(&psum[lane * 4 + 3], v.w);
        }
    }
    if (POOL) {
        __syncthreads();
        if (threadIdx.x < 64)
            partials[(size_t)blockIdx.x * 64 + threadIdx.x] = psum[threadIdx.x];
    }
}

// ===========================================================================
// Final mean-pool: out[f] = sum_blocks(partials)/N + b2[f]
// ===========================================================================
__global__ __launch_bounds__(256) void pool_final_kernel(
    const float* __restrict__ partials, const float* __restrict__ b2,
    float* __restrict__ out, int nblk, int N)
{
    __shared__ float red[256];
    const int f = threadIdx.x & 63;
    const int sub = threadIdx.x >> 6;
    float acc = 0.f;
    for (int r = blockIdx.x * 4 + sub; r < nblk; r += gridDim.x * 4)
        acc += partials[(size_t)r * 64 + f];
    red[threadIdx.x] = acc;
    __syncthreads();
    if (threadIdx.x < 64) {
        float s = red[f] + red[64 + f] + red[128 + f] + red[192 + f];
        atomicAdd(out + f, s * (1.0f / (float)N));
        if (blockIdx.x == 0) atomicAdd(out + f, b2[f]);
    }
}

extern "C" void kernel_launch(void* const* d_in, const int* in_sizes, int n_in,
                              void* d_out, int out_size, void* d_ws, size_t ws_size,
                              hipStream_t stream) {
    const float* x   = (const float*)d_in[0];
    const int*   ei  = (const int*)d_in[1];
    const float* W1  = (const float*)d_in[3];
    const float* as1 = (const float*)d_in[4];
    const float* ad1 = (const float*)d_in[5];
    const float* b1  = (const float*)d_in[6];
    const float* W2  = (const float*)d_in[7];
    const float* as2 = (const float*)d_in[8];
    const float* ad2 = (const float*)d_in[9];
    const float* b2  = (const float*)d_in[10];
    float* out = (float*)d_out;

    const int N = in_sizes[0] / 128;     // 100000
    const int E = in_sizes[1] / 2;       // 1600000
    const int NB = (N + 63) >> BSHIFT;   // 1563 buckets
    const int NBLK = (E + CHUNK - 1) / CHUNK;  // 391 binning blocks
    const int agg_blocks = (int)(((size_t)N * 16 + 255) / 256);   // 6250

    auto align4 = [](size_t v) { return (v + 3) & ~(size_t)3; };
    float* ws    = (float*)d_ws;
    size_t off = 0;
    unsigned short* hb = (unsigned short*)(ws + off); off += align4((size_t)N * 32);
    unsigned short* gb = (unsigned short*)(ws + off); off += align4((size_t)N * 32);
    float* asrc  = ws + off; off += align4(N);
    float* adst  = ws + off; off += align4(N);
    int* row_beg = (int*)(ws + off); off += align4(N);
    int* row_end = (int*)(ws + off); off += align4(N);
    int* btotal  = (int*)(ws + off); off += NBMAX;
    unsigned short* wb1 = (unsigned short*)(ws + off); off += align4(64 * 128 / 2);
    unsigned short* wb2 = (unsigned short*)(ws + off); off += align4(64 * 64 / 2);
    float* partials = ws + off; off += align4((size_t)agg_blocks * 64);
    int* hist    = (int*)(ws + off); off += align4((size_t)NBLK * NB);
    int* esrc    = (int*)(ws + off); off += align4((size_t)NB * ESTRIDE);
    int* binned  = (int*)gb;  // alias: gb dead until aggregate-1 writes it

    const int gemm_blocks = (N + 63) / 64;

    hipMemsetAsync(out, 0, 64 * sizeof(float), stream);
    wconv_kernel<<<48, 256, 0, stream>>>(W1, W2, wb1, wb2);

    // ---- CSR build: 4 kernels, zero contended global atomics ----
    hist_kernel<<<NBLK, 256, 0, stream>>>(ei, hist, E, NB);
    colscan_kernel<<<(NB + 255) / 256, 256, 0, stream>>>(hist, btotal, NB, NBLK);
    scatter_kernel<<<NBLK, 256, 0, stream>>>(ei, hist, binned, E, NB);
    bucket_csr_kernel<<<NB, 256, 0, stream>>>(binned, btotal, row_beg, row_end, esrc, N);

    // ---- layer 1 ----
    gemm_attn_kernel<128, false><<<gemm_blocks, 256, 0, stream>>>(
        x, wb1, as1, ad1, hb, asrc, adst, N);
    aggregate_csr_kernel<false><<<agg_blocks, 256, 0, stream>>>(
        row_beg, row_end, esrc, asrc, adst, hb, b1, gb, nullptr, N);

    // ---- layer 2 (aggregation fused with pooling partials) ----
    gemm_attn_kernel<64, true><<<gemm_blocks, 256, 0, stream>>>(
        gb, wb2, as2, ad2, hb, asrc, adst, N);
    aggregate_csr_kernel<true><<<agg_blocks, 256, 0, stream>>>(
        row_beg, row_end, esrc, asrc, adst, hb, nullptr, nullptr, partials, N);

    // ---- final mean pool + bias ----
    pool_final_kernel<<<64, 256, 0, stream>>>(partials, b2, out, agg_blocks, N);
}